// Round 16
// baseline (122.905 us; speedup 1.0000x reference)
//
#include <hip/hip_runtime.h>
#include <cstdint>
#include <cstddef>

#define Bb   2
#define Nn   1024
#define Hh   8
#define DHh  64
#define DMm  512
#define TOPK 102   // int(1024 * (1.0 - 0.9)) == 102

typedef __attribute__((ext_vector_type(8))) short          bf16x8;
typedef __attribute__((ext_vector_type(4))) float          f32x4;
typedef __attribute__((ext_vector_type(8))) unsigned short us8;
typedef __attribute__((ext_vector_type(4))) unsigned short us4;

// ---------------------------------------------------------------------------
// Exact 3-way bf16 split: a = h + m + l captures 24 mantissa bits.
// ---------------------------------------------------------------------------
__device__ __forceinline__ void split3(float a, unsigned short& h,
                                       unsigned short& m, unsigned short& l) {
  unsigned int ab = __float_as_uint(a);
  h = (unsigned short)(ab >> 16);
  float r = a - __uint_as_float(ab & 0xFFFF0000u);
  unsigned int rb = __float_as_uint(r);
  m = (unsigned short)(rb >> 16);
  float r2 = r - __uint_as_float(rb & 0xFFFF0000u);
  l = (unsigned short)(__float_as_uint(r2) >> 16);
}

// ---------------------------------------------------------------------------
// Split x (1M el) + Wq/Wk/Wv/Wo (256K each) into bf16 h/m/l planes.
// ---------------------------------------------------------------------------
__global__ __launch_bounds__(256) void cvt_split5(
    const float* __restrict__ x,
    const float* __restrict__ Wq, const float* __restrict__ Wk,
    const float* __restrict__ Wv, const float* __restrict__ Wo,
    unsigned short* __restrict__ xpl, unsigned short* __restrict__ wpl) {
  const int e4 = (blockIdx.x * 256 + threadIdx.x) << 2;
  const float* src;
  unsigned short *dh, *dm, *dl;
  int off;
  if (e4 < 1048576) {
    src = x; off = e4;
    dh = xpl; dm = xpl + 1048576; dl = xpl + 2097152;
  } else {
    int r = e4 - 1048576;
    int t = r >> 18;
    off = r & 262143;
    src = (t == 0) ? Wq : (t == 1) ? Wk : (t == 2) ? Wv : Wo;
    unsigned short* base = wpl + (size_t)t * 786432;
    dh = base; dm = base + 262144; dl = base + 524288;
  }
  const float4 a = *(const float4*)(src + off);
  const float av[4] = {a.x, a.y, a.z, a.w};
  us4 vh, vm, vl;
#pragma unroll
  for (int j = 0; j < 4; ++j) {
    unsigned short th, tm, tl;
    split3(av[j], th, tm, tl);
    vh[j] = th; vm[j] = tm; vl[j] = tl;
  }
  *(us4*)(dh + off) = vh;
  *(us4*)(dm + off) = vm;
  *(us4*)(dl + off) = vl;
}

// ---------------------------------------------------------------------------
// C = A @ W^T via bf16x3 MFMA. z==0,1 (q,k): 6 products (exact, feeds LSH
// signs). z==2 (v): 3 products (hh,hm,mh — output-only fidelity, 1.5e-5 rel).
// Block 64x64, 4 waves 2x2, wave tile 32x32 = 2x2 mfma_f32_16x16x32_bf16.
// C/D layout (verified m89/m91): col = lane&15, row = (lane>>4)*4 + reg.
// ---------------------------------------------------------------------------
__global__ __launch_bounds__(256) void gemm_bf16x3(
    const unsigned short* __restrict__ Ap,
    const unsigned short* __restrict__ Wt,
    float* __restrict__ Cb) {
  __shared__ unsigned short lds[6][2560];     // 6 x [64][40] halfs = 30 KB
  const int tid = threadIdx.x;
  const int w   = tid >> 6;
  const int l   = tid & 63;
  const int bm  = blockIdx.x << 6;
  const int z   = blockIdx.y >> 3;
  const int bn  = (blockIdx.y & 7) << 6;
  const unsigned short* __restrict__ Wp = Wt + (size_t)z * 786432;
  float* __restrict__ C = Cb + (size_t)z * 1048576;
  const int np = (z == 2) ? 2 : 3;            // planes staged/used

  const int wr   = w >> 1, wc = w & 1;
  const int srow = tid >> 2;          // 0..63
  const int sc8  = (tid & 3) << 3;    // 0,8,16,24
  const int lrow = l & 15;
  const int lk8  = (l >> 4) << 3;

  f32x4 acc[2][2] = {};

  for (int ks = 0; ks < 16; ++ks) {
    const int k0 = ks << 5;
    __syncthreads();
#pragma unroll
    for (int p = 0; p < 3; ++p) {
      if (p < np) {
        const us8 av = *(const us8*)(Ap + (size_t)p * 1048576 +
                                     (size_t)(bm + srow) * 512 + k0 + sc8);
        *(us8*)&lds[p][srow * 40 + sc8] = av;
        const us8 wv = *(const us8*)(Wp + (size_t)p * 262144 +
                                     (size_t)(bn + srow) * 512 + k0 + sc8);
        *(us8*)&lds[3 + p][srow * 40 + sc8] = wv;
      }
    }
    __syncthreads();
    bf16x8 aF[2][3], bF[2][3];
#pragma unroll
    for (int t2 = 0; t2 < 2; ++t2)
#pragma unroll
      for (int p = 0; p < 3; ++p) {
        if (p < np) {
          aF[t2][p] = *(const bf16x8*)&lds[p][(wr * 32 + t2 * 16 + lrow) * 40 + lk8];
          bF[t2][p] = *(const bf16x8*)&lds[3 + p][(wc * 32 + t2 * 16 + lrow) * 40 + lk8];
        }
      }
#pragma unroll
    for (int rt = 0; rt < 2; ++rt)
#pragma unroll
      for (int ct = 0; ct < 2; ++ct) {
        f32x4 a = acc[rt][ct];
        a = __builtin_amdgcn_mfma_f32_16x16x32_bf16(aF[rt][0], bF[ct][0], a, 0, 0, 0);
        a = __builtin_amdgcn_mfma_f32_16x16x32_bf16(aF[rt][0], bF[ct][1], a, 0, 0, 0);
        a = __builtin_amdgcn_mfma_f32_16x16x32_bf16(aF[rt][1], bF[ct][0], a, 0, 0, 0);
        if (np == 3) {
          a = __builtin_amdgcn_mfma_f32_16x16x32_bf16(aF[rt][0], bF[ct][2], a, 0, 0, 0);
          a = __builtin_amdgcn_mfma_f32_16x16x32_bf16(aF[rt][1], bF[ct][1], a, 0, 0, 0);
          a = __builtin_amdgcn_mfma_f32_16x16x32_bf16(aF[rt][2], bF[ct][0], a, 0, 0, 0);
        }
        acc[rt][ct] = a;
      }
  }
#pragma unroll
  for (int rt = 0; rt < 2; ++rt)
#pragma unroll
    for (int ct = 0; ct < 2; ++ct)
#pragma unroll
      for (int r = 0; r < 4; ++r) {
        const int row = bm + wr * 32 + rt * 16 + (l >> 4) * 4 + r;
        const int col = bn + wc * 32 + ct * 16 + (l & 15);
        C[(size_t)row * 512 + col] = acc[rt][ct][r];
      }
}

// ---------------------------------------------------------------------------
// out = ao @ Wo^T via bf16x2 (3 products: hh, hm, mh). ao planes [2][1M],
// Wo planes h,m at Wp, Wp+262144. Same tile geometry as gemm_bf16x3.
// ---------------------------------------------------------------------------
__global__ __launch_bounds__(256) void gemm_ao_bf16x2(
    const unsigned short* __restrict__ Ap,
    const unsigned short* __restrict__ Wp,
    float* __restrict__ C) {
  __shared__ unsigned short lds[4][2560];     // 4 x [64][40] halfs = 20 KB
  const int tid = threadIdx.x;
  const int w   = tid >> 6;
  const int l   = tid & 63;
  const int bm  = blockIdx.x << 6;
  const int bn  = blockIdx.y << 6;

  const int wr   = w >> 1, wc = w & 1;
  const int srow = tid >> 2;
  const int sc8  = (tid & 3) << 3;
  const int lrow = l & 15;
  const int lk8  = (l >> 4) << 3;

  f32x4 acc[2][2] = {};

  for (int ks = 0; ks < 16; ++ks) {
    const int k0 = ks << 5;
    __syncthreads();
#pragma unroll
    for (int p = 0; p < 2; ++p) {
      const us8 av = *(const us8*)(Ap + (size_t)p * 1048576 +
                                   (size_t)(bm + srow) * 512 + k0 + sc8);
      *(us8*)&lds[p][srow * 40 + sc8] = av;
      const us8 wv = *(const us8*)(Wp + (size_t)p * 262144 +
                                   (size_t)(bn + srow) * 512 + k0 + sc8);
      *(us8*)&lds[2 + p][srow * 40 + sc8] = wv;
    }
    __syncthreads();
    bf16x8 aF[2][2], bF[2][2];
#pragma unroll
    for (int t2 = 0; t2 < 2; ++t2)
#pragma unroll
      for (int p = 0; p < 2; ++p) {
        aF[t2][p] = *(const bf16x8*)&lds[p][(wr * 32 + t2 * 16 + lrow) * 40 + lk8];
        bF[t2][p] = *(const bf16x8*)&lds[2 + p][(wc * 32 + t2 * 16 + lrow) * 40 + lk8];
      }
#pragma unroll
    for (int rt = 0; rt < 2; ++rt)
#pragma unroll
      for (int ct = 0; ct < 2; ++ct) {
        f32x4 a = acc[rt][ct];
        a = __builtin_amdgcn_mfma_f32_16x16x32_bf16(aF[rt][0], bF[ct][0], a, 0, 0, 0);
        a = __builtin_amdgcn_mfma_f32_16x16x32_bf16(aF[rt][0], bF[ct][1], a, 0, 0, 0);
        a = __builtin_amdgcn_mfma_f32_16x16x32_bf16(aF[rt][1], bF[ct][0], a, 0, 0, 0);
        acc[rt][ct] = a;
      }
  }
#pragma unroll
  for (int rt = 0; rt < 2; ++rt)
#pragma unroll
    for (int ct = 0; ct < 2; ++ct)
#pragma unroll
      for (int r = 0; r < 4; ++r) {
        const int row = bm + wr * 32 + rt * 16 + (l >> 4) * 4 + r;
        const int col = bn + wc * 32 + ct * 16 + (l & 15);
        C[(size_t)row * 512 + col] = acc[rt][ct][r];
      }
}

// ---------------------------------------------------------------------------
// Hash + norms: one wave per (b,h,n) row. lane = head-dim d.
// ---------------------------------------------------------------------------
__global__ __launch_bounds__(256) void hash_norm_kernel(
    const float* __restrict__ q, const float* __restrict__ k,
    const float* __restrict__ rv,
    uint32_t* __restrict__ qh, uint32_t* __restrict__ kh,
    float* __restrict__ qn, float* __restrict__ kn) {
  const int wid  = threadIdx.x >> 6;
  const int lane = threadIdx.x & 63;
  const int row  = blockIdx.x * 4 + wid;      // b*H*N + h*N + n
  const int n    = row & (Nn - 1);
  const int bh   = row >> 10;
  const int b    = bh >> 3, h = bh & 7;
  const size_t off = (size_t)(b * Nn + n) * DMm + h * DHh + lane;
  const float qd = q[off], kd = k[off];
  float acc[18];
#pragma unroll
  for (int t = 0; t < 8; ++t) {
    float r = rv[t * DHh + lane];
    acc[t]     = qd * r;
    acc[8 + t] = kd * r;
  }
  acc[16] = qd * qd;
  acc[17] = kd * kd;
#pragma unroll
  for (int i = 0; i < 18; ++i) {
#pragma unroll
    for (int s = 1; s < 64; s <<= 1) acc[i] += __shfl_xor(acc[i], s);
  }
  if (lane == 0) {
    uint32_t qb = 0, kb = 0;
#pragma unroll
    for (int t = 0; t < 8; ++t) {
      qb |= (acc[t]     >= 0.f ? 1u : 0u) << t;
      kb |= (acc[8 + t] >= 0.f ? 1u : 0u) << t;
    }
    qh[row] = qb; kh[row] = kb;
    qn[row] = acc[16]; kn[row] = acc[17];
  }
}

// ---------------------------------------------------------------------------
// Attention: one wave per (b,h,n) row; XCD-affinity swizzle. SINGLE-PASS
// gather loop: per key, K-row + V-row + kn gathered together; dot via
// 3-shuffle group reduce (all 8 lanes get the sum); weight w = 1/(c+sqrt(c^2-1))
// computed per-lane (exact duplicates); oa += w*v and wsum += w accumulated
// in the same iteration. No dw LDS round-trip, no separate phases B/C.
// wsum lane-duplication is exactly 8x (power-of-2 scaling) -> inv uses 0.125.
// Epilogue writes TWO bf16 planes of ao (h,m) for the bf16x2 Wo GEMM.
// ---------------------------------------------------------------------------
__global__ __launch_bounds__(256) void attn_wave_kernel(
    const float* __restrict__ q, const float* __restrict__ k,
    const float* __restrict__ v,
    const uint32_t* __restrict__ qh, const uint32_t* __restrict__ kh,
    const float* __restrict__ qn, const float* __restrict__ kn,
    unsigned short* __restrict__ aopl) {
  const int wid  = threadIdx.x >> 6;
  const int lane = threadIdx.x & 63;
  const int bid  = blockIdx.x;            // 0..4095
  const int xcd  = bid & 7;
  const int slot = bid >> 3;              // 0..511
  const int bh   = xcd + ((slot >> 8) << 3);
  const int nb   = slot & 255;
  const int row  = (bh << 10) + (nb << 2) + wid;
  const int n    = row & (Nn - 1);
  const int b    = bh >> 3, h = bh & 7;

  __shared__ int sel[4][104];

  const uint32_t myh = qh[row];
  const uint32_t* __restrict__ krh = kh + (bh << 10);

  int m[16];
#pragma unroll
  for (int c = 0; c < 16; ++c)
    m[c] = 8 - __popc(myh ^ krh[(c << 6) + lane]);

  uint32_t p0 = 0, p1 = 0, p2 = 0;
#pragma unroll
  for (int c = 0; c < 16; ++c) {
    uint32_t one = 1u << ((m[c] & 3) << 3);
    int gq = m[c] >> 2;
    p0 += (gq == 0) ? one : 0u;
    p1 += (gq == 1) ? one : 0u;
    p2 += (gq == 2) ? one : 0u;
  }
#pragma unroll
  for (int s = 1; s < 8; s <<= 1) {
    p0 += __shfl_xor(p0, s);
    p1 += __shfl_xor(p1, s);
    p2 += __shfl_xor(p2, s);
  }
  uint32_t hr[5];
  hr[0] = (p0 & 0xffu) | (((p0 >> 8) & 0xffu) << 16);
  hr[1] = ((p0 >> 16) & 0xffu) | (((p0 >> 24) & 0xffu) << 16);
  hr[2] = (p1 & 0xffu) | (((p1 >> 8) & 0xffu) << 16);
  hr[3] = ((p1 >> 16) & 0xffu) | (((p1 >> 24) & 0xffu) << 16);
  hr[4] = p2 & 0xffu;
#pragma unroll
  for (int i = 0; i < 5; ++i) {
#pragma unroll
    for (int s = 8; s < 64; s <<= 1) hr[i] += __shfl_xor(hr[i], s);
  }
  int cnt[9];
#pragma unroll
  for (int i = 0; i < 4; ++i) {
    cnt[2 * i]     = hr[i] & 0xffffu;
    cnt[2 * i + 1] = hr[i] >> 16;
  }
  cnt[8] = hr[4] & 0xffffu;

  int thr = 0, R = TOPK, gtc = 0;
  {
    int cum = 0; bool done = false;
#pragma unroll
    for (int mv = 8; mv >= 0; --mv) {
      int cx = cnt[mv];
      if (!done && cum + cx >= TOPK) { thr = mv; R = TOPK - cum; gtc = cum; done = true; }
      if (!done) cum += cx;
    }
  }

  const unsigned long long ltm = (1ULL << lane) - 1ULL;
  int bgt = 0, beq = 0;
#pragma unroll
  for (int c = 0; c < 16; ++c) {
    bool gt = m[c] > thr, eq = m[c] == thr;
    unsigned long long mg = __ballot(gt);
    unsigned long long me = __ballot(eq);
    int rg = bgt + __popcll(mg & ltm);
    int re = beq + __popcll(me & ltm);
    int j = (c << 6) + lane;
    if (gt) sel[wid][rg] = j;
    else if (eq && re < R) sel[wid][gtc + re] = j;
    bgt += __popcll(mg);
    beq += __popcll(me);
  }
  __builtin_amdgcn_wave_barrier();

  const int g  = lane >> 3;
  const int gl = lane & 7;
  const float* __restrict__ qrow = q + (size_t)(b * Nn + n) * DMm + h * DHh + gl * 8;
  const float4 qt0 = *(const float4*)qrow;
  const float4 qt1 = *(const float4*)(qrow + 4);
  const float qv[8] = {qt0.x, qt0.y, qt0.z, qt0.w, qt1.x, qt1.y, qt1.z, qt1.w};
  const float qnrm = qn[row];
  const float oneq = 1.f - qnrm;
  const float* __restrict__ kbh = k + (size_t)b * Nn * DMm + h * DHh;
  const float* __restrict__ vbh = v + (size_t)b * Nn * DMm + h * DHh;
  const float* __restrict__ knb = kn + (bh << 10);

  // single-pass: gather K+V+kn, dot, weight, accumulate — 13 rounds total
  float oa[8] = {};
  float wsum = 0.f;
#pragma unroll
  for (int it = 0; it < 13; ++it) {
    const int s = it * 8 + g;
    const bool act = s < TOPK;
    const int j = act ? sel[wid][s] : sel[wid][0];
    const float* __restrict__ kr = kbh + (size_t)j * DMm + gl * 8;
    const float* __restrict__ vr = vbh + (size_t)j * DMm + gl * 8;
    const float4 k0 = *(const float4*)kr;
    const float4 k1 = *(const float4*)(kr + 4);
    const float4 v0 = *(const float4*)vr;
    const float4 v1 = *(const float4*)(vr + 4);
    const float knj = knb[j];
    float dot = k0.x * qv[0];
    dot = fmaf(k0.y, qv[1], dot);
    dot = fmaf(k0.z, qv[2], dot);
    dot = fmaf(k0.w, qv[3], dot);
    dot = fmaf(k1.x, qv[4], dot);
    dot = fmaf(k1.y, qv[5], dot);
    dot = fmaf(k1.z, qv[6], dot);
    dot = fmaf(k1.w, qv[7], dot);
    dot += __shfl_xor(dot, 1);
    dot += __shfl_xor(dot, 2);
    dot += __shfl_xor(dot, 4);        // all 8 lanes of the group hold the sum
    float dsq = fmaxf(qnrm + knj - 2.f * dot, 0.f);
    float den = fmaxf(oneq * (1.f - knj), 1e-6f);
    float cc  = fmaxf(fmaf(2.f * dsq, __builtin_amdgcn_rcpf(den), 1.f), 1.f);
    float zz  = cc + __builtin_amdgcn_sqrtf(fmaf(cc, cc, -1.f));
    const float w = act ? __builtin_amdgcn_rcpf(zz) : 0.f;
    wsum += w;
    oa[0] = fmaf(w, v0.x, oa[0]);
    oa[1] = fmaf(w, v0.y, oa[1]);
    oa[2] = fmaf(w, v0.z, oa[2]);
    oa[3] = fmaf(w, v0.w, oa[3]);
    oa[4] = fmaf(w, v1.x, oa[4]);
    oa[5] = fmaf(w, v1.y, oa[5]);
    oa[6] = fmaf(w, v1.z, oa[6]);
    oa[7] = fmaf(w, v1.w, oa[7]);
  }
  // wsum: each group's w is duplicated on 8 lanes -> full-wave reduce is
  // exactly 8x the true sum (power-of-2 doublings are exact).
#pragma unroll
  for (int s = 1; s < 64; s <<= 1) wsum += __shfl_xor(wsum, s);
  const float inv = __builtin_amdgcn_rcpf(wsum * 0.125f);
  // oa cross-group reduce (lanes with same gl across the 8 groups)
#pragma unroll
  for (int s = 8; s < 64; s <<= 1) {
#pragma unroll
    for (int d = 0; d < 8; ++d) oa[d] += __shfl_xor(oa[d], s);
  }
  if (g == 0) {
    // fused epilogue: write bf16x2 planes (h,m) of ao
    const size_t off = (size_t)(b * Nn + n) * DMm + h * DHh + gl * 8;
    us4 h0, h1, m0v, m1v;
#pragma unroll
    for (int d = 0; d < 4; ++d) {
      unsigned short th, tm, tl;
      split3(oa[d] * inv, th, tm, tl);
      h0[d] = th; m0v[d] = tm;
      split3(oa[4 + d] * inv, th, tm, tl);
      h1[d] = th; m1v[d] = tm;
    }
    *(us4*)(aopl + off)               = h0;
    *(us4*)(aopl + off + 4)           = h1;
    *(us4*)(aopl + 1048576 + off)     = m0v;
    *(us4*)(aopl + 1048576 + off + 4) = m1v;
  }
}

// ---------------------------------------------------------------------------
extern "C" void kernel_launch(void* const* d_in, const int* in_sizes, int n_in,
                              void* d_out, int out_size, void* d_ws, size_t ws_size,
                              hipStream_t stream) {
  const float* x  = (const float*)d_in[0];
  const float* Wq = (const float*)d_in[1];
  const float* Wk = (const float*)d_in[2];
  const float* Wv = (const float*)d_in[3];
  const float* Wo = (const float*)d_in[4];
  const float* rv = (const float*)d_in[5];
  float* outp = (float*)d_out;

  const int RWS = Bb * Hh * Nn;  // 16384 (b,h,n) rows
  char* wsb = (char*)d_ws;
  float* q  = (float*)wsb;                 // 3 x 1M f32 (QKV)
  float* k  = q + 1048576;
  float* v  = k + 1048576;
  uint32_t* qh = (uint32_t*)(v + 1048576);
  uint32_t* kh = qh + RWS;
  float* qn = (float*)(kh + RWS);
  float* kn = qn + RWS;
  unsigned short* xpl = (unsigned short*)(wsb + (size_t)14 * 1024 * 1024);  // 3x1M halfs; reused as ao planes (h,m)
  unsigned short* wpl = xpl + (size_t)3 * 1048576;                          // 4x3x256K halfs

  cvt_split5<<<2048, 256, 0, stream>>>(x, Wq, Wk, Wv, Wo, xpl, wpl);
  dim3 gq(32, 24);               // QKV fused: z = blockIdx.y>>3 (z==2 -> 3 products)
  gemm_bf16x3<<<gq, 256, 0, stream>>>(xpl, wpl, q);
  hash_norm_kernel<<<RWS / 4, 256, 0, stream>>>(q, k, rv, qh, kh, qn, kn);
  attn_wave_kernel<<<RWS / 4, 256, 0, stream>>>(q, k, v, qh, kh, qn, kn, xpl);
  dim3 go(32, 8);
  gemm_ao_bf16x2<<<go, 256, 0, stream>>>(xpl, wpl + (size_t)3 * 786432, outp);
}

// Round 17
// 108.902 us; speedup vs baseline: 1.1286x; 1.1286x over previous
//
#include <hip/hip_runtime.h>
#include <cstdint>
#include <cstddef>

#define Bb   2
#define Nn   1024
#define Hh   8
#define DHh  64
#define DMm  512
#define TOPK 102   // int(1024 * (1.0 - 0.9)) == 102

typedef __attribute__((ext_vector_type(8))) short          bf16x8;
typedef __attribute__((ext_vector_type(4))) float          f32x4;
typedef __attribute__((ext_vector_type(8))) unsigned short us8;
typedef __attribute__((ext_vector_type(4))) unsigned short us4;

// ---------------------------------------------------------------------------
// Exact 3-way bf16 split: a = h + m + l captures 24 mantissa bits.
// ---------------------------------------------------------------------------
__device__ __forceinline__ void split3(float a, unsigned short& h,
                                       unsigned short& m, unsigned short& l) {
  unsigned int ab = __float_as_uint(a);
  h = (unsigned short)(ab >> 16);
  float r = a - __uint_as_float(ab & 0xFFFF0000u);
  unsigned int rb = __float_as_uint(r);
  m = (unsigned short)(rb >> 16);
  float r2 = r - __uint_as_float(rb & 0xFFFF0000u);
  l = (unsigned short)(__float_as_uint(r2) >> 16);
}

// ---------------------------------------------------------------------------
// Split x (1M el) + Wq/Wk/Wv/Wo (256K each) into bf16 h/m/l planes.
// ---------------------------------------------------------------------------
__global__ __launch_bounds__(256) void cvt_split5(
    const float* __restrict__ x,
    const float* __restrict__ Wq, const float* __restrict__ Wk,
    const float* __restrict__ Wv, const float* __restrict__ Wo,
    unsigned short* __restrict__ xpl, unsigned short* __restrict__ wpl) {
  const int e4 = (blockIdx.x * 256 + threadIdx.x) << 2;
  const float* src;
  unsigned short *dh, *dm, *dl;
  int off;
  if (e4 < 1048576) {
    src = x; off = e4;
    dh = xpl; dm = xpl + 1048576; dl = xpl + 2097152;
  } else {
    int r = e4 - 1048576;
    int t = r >> 18;
    off = r & 262143;
    src = (t == 0) ? Wq : (t == 1) ? Wk : (t == 2) ? Wv : Wo;
    unsigned short* base = wpl + (size_t)t * 786432;
    dh = base; dm = base + 262144; dl = base + 524288;
  }
  const float4 a = *(const float4*)(src + off);
  const float av[4] = {a.x, a.y, a.z, a.w};
  us4 vh, vm, vl;
#pragma unroll
  for (int j = 0; j < 4; ++j) {
    unsigned short th, tm, tl;
    split3(av[j], th, tm, tl);
    vh[j] = th; vm[j] = tm; vl[j] = tl;
  }
  *(us4*)(dh + off) = vh;
  *(us4*)(dm + off) = vm;
  *(us4*)(dl + off) = vl;
}

// ---------------------------------------------------------------------------
// C = A @ W^T via bf16x3 MFMA. z==0,1 (q,k): 6 products (exact, feeds LSH
// signs). z==2 (v): 3 products (hh,hm,mh — output-only fidelity, 1.5e-5 rel).
// Block 64x64, 4 waves 2x2, wave tile 32x32 = 2x2 mfma_f32_16x16x32_bf16.
// C/D layout (verified m89/m91): col = lane&15, row = (lane>>4)*4 + reg.
// ---------------------------------------------------------------------------
__global__ __launch_bounds__(256) void gemm_bf16x3(
    const unsigned short* __restrict__ Ap,
    const unsigned short* __restrict__ Wt,
    float* __restrict__ Cb) {
  __shared__ unsigned short lds[6][2560];     // 6 x [64][40] halfs = 30 KB
  const int tid = threadIdx.x;
  const int w   = tid >> 6;
  const int l   = tid & 63;
  const int bm  = blockIdx.x << 6;
  const int z   = blockIdx.y >> 3;
  const int bn  = (blockIdx.y & 7) << 6;
  const unsigned short* __restrict__ Wp = Wt + (size_t)z * 786432;
  float* __restrict__ C = Cb + (size_t)z * 1048576;
  const int np = (z == 2) ? 2 : 3;            // planes staged/used

  const int wr   = w >> 1, wc = w & 1;
  const int srow = tid >> 2;          // 0..63
  const int sc8  = (tid & 3) << 3;    // 0,8,16,24
  const int lrow = l & 15;
  const int lk8  = (l >> 4) << 3;

  f32x4 acc[2][2] = {};

  for (int ks = 0; ks < 16; ++ks) {
    const int k0 = ks << 5;
    __syncthreads();
#pragma unroll
    for (int p = 0; p < 3; ++p) {
      if (p < np) {
        const us8 av = *(const us8*)(Ap + (size_t)p * 1048576 +
                                     (size_t)(bm + srow) * 512 + k0 + sc8);
        *(us8*)&lds[p][srow * 40 + sc8] = av;
        const us8 wv = *(const us8*)(Wp + (size_t)p * 262144 +
                                     (size_t)(bn + srow) * 512 + k0 + sc8);
        *(us8*)&lds[3 + p][srow * 40 + sc8] = wv;
      }
    }
    __syncthreads();
    bf16x8 aF[2][3], bF[2][3];
#pragma unroll
    for (int t2 = 0; t2 < 2; ++t2)
#pragma unroll
      for (int p = 0; p < 3; ++p) {
        if (p < np) {
          aF[t2][p] = *(const bf16x8*)&lds[p][(wr * 32 + t2 * 16 + lrow) * 40 + lk8];
          bF[t2][p] = *(const bf16x8*)&lds[3 + p][(wc * 32 + t2 * 16 + lrow) * 40 + lk8];
        }
      }
#pragma unroll
    for (int rt = 0; rt < 2; ++rt)
#pragma unroll
      for (int ct = 0; ct < 2; ++ct) {
        f32x4 a = acc[rt][ct];
        a = __builtin_amdgcn_mfma_f32_16x16x32_bf16(aF[rt][0], bF[ct][0], a, 0, 0, 0);
        a = __builtin_amdgcn_mfma_f32_16x16x32_bf16(aF[rt][0], bF[ct][1], a, 0, 0, 0);
        a = __builtin_amdgcn_mfma_f32_16x16x32_bf16(aF[rt][1], bF[ct][0], a, 0, 0, 0);
        if (np == 3) {
          a = __builtin_amdgcn_mfma_f32_16x16x32_bf16(aF[rt][0], bF[ct][2], a, 0, 0, 0);
          a = __builtin_amdgcn_mfma_f32_16x16x32_bf16(aF[rt][1], bF[ct][1], a, 0, 0, 0);
          a = __builtin_amdgcn_mfma_f32_16x16x32_bf16(aF[rt][2], bF[ct][0], a, 0, 0, 0);
        }
        acc[rt][ct] = a;
      }
  }
#pragma unroll
  for (int rt = 0; rt < 2; ++rt)
#pragma unroll
    for (int ct = 0; ct < 2; ++ct)
#pragma unroll
      for (int r = 0; r < 4; ++r) {
        const int row = bm + wr * 32 + rt * 16 + (l >> 4) * 4 + r;
        const int col = bn + wc * 32 + ct * 16 + (l & 15);
        C[(size_t)row * 512 + col] = acc[rt][ct][r];
      }
}

// ---------------------------------------------------------------------------
// out = ao @ Wo^T via bf16x2 (3 products: hh, hm, mh). ao planes [2][1M],
// Wo planes h,m at Wp, Wp+262144. Same tile geometry as gemm_bf16x3.
// ---------------------------------------------------------------------------
__global__ __launch_bounds__(256) void gemm_ao_bf16x2(
    const unsigned short* __restrict__ Ap,
    const unsigned short* __restrict__ Wp,
    float* __restrict__ C) {
  __shared__ unsigned short lds[4][2560];     // 4 x [64][40] halfs = 20 KB
  const int tid = threadIdx.x;
  const int w   = tid >> 6;
  const int l   = tid & 63;
  const int bm  = blockIdx.x << 6;
  const int bn  = blockIdx.y << 6;

  const int wr   = w >> 1, wc = w & 1;
  const int srow = tid >> 2;
  const int sc8  = (tid & 3) << 3;
  const int lrow = l & 15;
  const int lk8  = (l >> 4) << 3;

  f32x4 acc[2][2] = {};

  for (int ks = 0; ks < 16; ++ks) {
    const int k0 = ks << 5;
    __syncthreads();
#pragma unroll
    for (int p = 0; p < 2; ++p) {
      const us8 av = *(const us8*)(Ap + (size_t)p * 1048576 +
                                   (size_t)(bm + srow) * 512 + k0 + sc8);
      *(us8*)&lds[p][srow * 40 + sc8] = av;
      const us8 wv = *(const us8*)(Wp + (size_t)p * 262144 +
                                   (size_t)(bn + srow) * 512 + k0 + sc8);
      *(us8*)&lds[2 + p][srow * 40 + sc8] = wv;
    }
    __syncthreads();
    bf16x8 aF[2][2], bF[2][2];
#pragma unroll
    for (int t2 = 0; t2 < 2; ++t2)
#pragma unroll
      for (int p = 0; p < 2; ++p) {
        aF[t2][p] = *(const bf16x8*)&lds[p][(wr * 32 + t2 * 16 + lrow) * 40 + lk8];
        bF[t2][p] = *(const bf16x8*)&lds[2 + p][(wc * 32 + t2 * 16 + lrow) * 40 + lk8];
      }
#pragma unroll
    for (int rt = 0; rt < 2; ++rt)
#pragma unroll
      for (int ct = 0; ct < 2; ++ct) {
        f32x4 a = acc[rt][ct];
        a = __builtin_amdgcn_mfma_f32_16x16x32_bf16(aF[rt][0], bF[ct][0], a, 0, 0, 0);
        a = __builtin_amdgcn_mfma_f32_16x16x32_bf16(aF[rt][0], bF[ct][1], a, 0, 0, 0);
        a = __builtin_amdgcn_mfma_f32_16x16x32_bf16(aF[rt][1], bF[ct][0], a, 0, 0, 0);
        acc[rt][ct] = a;
      }
  }
#pragma unroll
  for (int rt = 0; rt < 2; ++rt)
#pragma unroll
    for (int ct = 0; ct < 2; ++ct)
#pragma unroll
      for (int r = 0; r < 4; ++r) {
        const int row = bm + wr * 32 + rt * 16 + (l >> 4) * 4 + r;
        const int col = bn + wc * 32 + ct * 16 + (l & 15);
        C[(size_t)row * 512 + col] = acc[rt][ct][r];
      }
}

// ---------------------------------------------------------------------------
// Hash + norms: one wave per (b,h,n) row. lane = head-dim d.
// ---------------------------------------------------------------------------
__global__ __launch_bounds__(256) void hash_norm_kernel(
    const float* __restrict__ q, const float* __restrict__ k,
    const float* __restrict__ rv,
    uint32_t* __restrict__ qh, uint32_t* __restrict__ kh,
    float* __restrict__ qn, float* __restrict__ kn) {
  const int wid  = threadIdx.x >> 6;
  const int lane = threadIdx.x & 63;
  const int row  = blockIdx.x * 4 + wid;      // b*H*N + h*N + n
  const int n    = row & (Nn - 1);
  const int bh   = row >> 10;
  const int b    = bh >> 3, h = bh & 7;
  const size_t off = (size_t)(b * Nn + n) * DMm + h * DHh + lane;
  const float qd = q[off], kd = k[off];
  float acc[18];
#pragma unroll
  for (int t = 0; t < 8; ++t) {
    float r = rv[t * DHh + lane];
    acc[t]     = qd * r;
    acc[8 + t] = kd * r;
  }
  acc[16] = qd * qd;
  acc[17] = kd * kd;
#pragma unroll
  for (int i = 0; i < 18; ++i) {
#pragma unroll
    for (int s = 1; s < 64; s <<= 1) acc[i] += __shfl_xor(acc[i], s);
  }
  if (lane == 0) {
    uint32_t qb = 0, kb = 0;
#pragma unroll
    for (int t = 0; t < 8; ++t) {
      qb |= (acc[t]     >= 0.f ? 1u : 0u) << t;
      kb |= (acc[8 + t] >= 0.f ? 1u : 0u) << t;
    }
    qh[row] = qb; kh[row] = kb;
    qn[row] = acc[16]; kn[row] = acc[17];
  }
}

// ---------------------------------------------------------------------------
// Attention: one wave per (b,h,n) row; XCD-affinity swizzle; r13 structure
// (best measured: 57 us). Epilogue writes TWO bf16 planes of ao (h,m) for
// the bf16x2 Wo GEMM.
// softmax(-acosh(c)) == (1/z)/sum(1/z) with z = c + sqrt(c^2-1).
// ---------------------------------------------------------------------------
__global__ __launch_bounds__(256) void attn_wave_kernel(
    const float* __restrict__ q, const float* __restrict__ k,
    const float* __restrict__ v,
    const uint32_t* __restrict__ qh, const uint32_t* __restrict__ kh,
    const float* __restrict__ qn, const float* __restrict__ kn,
    unsigned short* __restrict__ aopl) {
  const int wid  = threadIdx.x >> 6;
  const int lane = threadIdx.x & 63;
  const int bid  = blockIdx.x;            // 0..4095
  const int xcd  = bid & 7;
  const int slot = bid >> 3;              // 0..511
  const int bh   = xcd + ((slot >> 8) << 3);
  const int nb   = slot & 255;
  const int row  = (bh << 10) + (nb << 2) + wid;
  const int n    = row & (Nn - 1);
  const int b    = bh >> 3, h = bh & 7;

  __shared__ int   sel[4][104];
  __shared__ float dw[4][104];

  const uint32_t myh = qh[row];
  const uint32_t* __restrict__ krh = kh + (bh << 10);

  int m[16];
#pragma unroll
  for (int c = 0; c < 16; ++c)
    m[c] = 8 - __popc(myh ^ krh[(c << 6) + lane]);

  uint32_t p0 = 0, p1 = 0, p2 = 0;
#pragma unroll
  for (int c = 0; c < 16; ++c) {
    uint32_t one = 1u << ((m[c] & 3) << 3);
    int gq = m[c] >> 2;
    p0 += (gq == 0) ? one : 0u;
    p1 += (gq == 1) ? one : 0u;
    p2 += (gq == 2) ? one : 0u;
  }
#pragma unroll
  for (int s = 1; s < 8; s <<= 1) {
    p0 += __shfl_xor(p0, s);
    p1 += __shfl_xor(p1, s);
    p2 += __shfl_xor(p2, s);
  }
  uint32_t hr[5];
  hr[0] = (p0 & 0xffu) | (((p0 >> 8) & 0xffu) << 16);
  hr[1] = ((p0 >> 16) & 0xffu) | (((p0 >> 24) & 0xffu) << 16);
  hr[2] = (p1 & 0xffu) | (((p1 >> 8) & 0xffu) << 16);
  hr[3] = ((p1 >> 16) & 0xffu) | (((p1 >> 24) & 0xffu) << 16);
  hr[4] = p2 & 0xffu;
#pragma unroll
  for (int i = 0; i < 5; ++i) {
#pragma unroll
    for (int s = 8; s < 64; s <<= 1) hr[i] += __shfl_xor(hr[i], s);
  }
  int cnt[9];
#pragma unroll
  for (int i = 0; i < 4; ++i) {
    cnt[2 * i]     = hr[i] & 0xffffu;
    cnt[2 * i + 1] = hr[i] >> 16;
  }
  cnt[8] = hr[4] & 0xffffu;

  int thr = 0, R = TOPK, gtc = 0;
  {
    int cum = 0; bool done = false;
#pragma unroll
    for (int mv = 8; mv >= 0; --mv) {
      int cx = cnt[mv];
      if (!done && cum + cx >= TOPK) { thr = mv; R = TOPK - cum; gtc = cum; done = true; }
      if (!done) cum += cx;
    }
  }

  const unsigned long long ltm = (1ULL << lane) - 1ULL;
  int bgt = 0, beq = 0;
#pragma unroll
  for (int c = 0; c < 16; ++c) {
    bool gt = m[c] > thr, eq = m[c] == thr;
    unsigned long long mg = __ballot(gt);
    unsigned long long me = __ballot(eq);
    int rg = bgt + __popcll(mg & ltm);
    int re = beq + __popcll(me & ltm);
    int j = (c << 6) + lane;
    if (gt) sel[wid][rg] = j;
    else if (eq && re < R) sel[wid][gtc + re] = j;
    bgt += __popcll(mg);
    beq += __popcll(me);
  }
  __builtin_amdgcn_wave_barrier();

  const int g  = lane >> 3;
  const int gl = lane & 7;
  const float* __restrict__ qrow = q + (size_t)(b * Nn + n) * DMm + h * DHh + gl * 8;
  const float4 qt0 = *(const float4*)qrow;
  const float4 qt1 = *(const float4*)(qrow + 4);
  const float qv[8] = {qt0.x, qt0.y, qt0.z, qt0.w, qt1.x, qt1.y, qt1.z, qt1.w};
  const float qnrm = qn[row];
  const float oneq = 1.f - qnrm;
  const float* __restrict__ kbh = k + (size_t)b * Nn * DMm + h * DHh;
  const float* __restrict__ knb = kn + (bh << 10);

  // Phase A: dots, 8 keys per iteration (8 groups x 8 lanes)
#pragma unroll
  for (int it = 0; it < 13; ++it) {
    int s = it * 8 + g;
    bool act = s < TOPK;
    int j = act ? sel[wid][s] : sel[wid][0];
    const float* __restrict__ kr = kbh + (size_t)j * DMm + gl * 8;
    const float4 k0 = *(const float4*)kr;
    const float4 k1 = *(const float4*)(kr + 4);
    const float kv[8] = {k0.x, k0.y, k0.z, k0.w, k1.x, k1.y, k1.z, k1.w};
    float dot = 0.f;
#pragma unroll
    for (int d = 0; d < 8; ++d) dot = fmaf(kv[d], qv[d], dot);
    dot += __shfl_xor(dot, 1);
    dot += __shfl_xor(dot, 2);
    dot += __shfl_xor(dot, 4);
    if (gl == 0 && act) dw[wid][s] = dot;
  }
  __builtin_amdgcn_wave_barrier();

  // Phase B: batched weights w = 1/(c + sqrt(c^2-1)), 2 keys per lane
  float w0, w1 = 0.f;
  {
    int j0 = sel[wid][lane];
    float dot0 = dw[wid][lane];
    float kn0 = knb[j0];
    float dsq = fmaxf(qnrm + kn0 - 2.f * dot0, 0.f);
    float den = fmaxf(oneq * (1.f - kn0), 1e-6f);
    float cc  = fmaxf(fmaf(2.f * dsq, __builtin_amdgcn_rcpf(den), 1.f), 1.f);
    float zz  = cc + __builtin_amdgcn_sqrtf(fmaf(cc, cc, -1.f));
    w0 = __builtin_amdgcn_rcpf(zz);
  }
  if (lane + 64 < TOPK) {
    int j1 = sel[wid][lane + 64];
    float dot1 = dw[wid][lane + 64];
    float kn1 = knb[j1];
    float dsq = fmaxf(qnrm + kn1 - 2.f * dot1, 0.f);
    float den = fmaxf(oneq * (1.f - kn1), 1e-6f);
    float cc  = fmaxf(fmaf(2.f * dsq, __builtin_amdgcn_rcpf(den), 1.f), 1.f);
    float zz  = cc + __builtin_amdgcn_sqrtf(fmaf(cc, cc, -1.f));
    w1 = __builtin_amdgcn_rcpf(zz);
  }
  float sm = w0 + w1;
#pragma unroll
  for (int s = 1; s < 64; s <<= 1) sm += __shfl_xor(sm, s);
  const float inv = __builtin_amdgcn_rcpf(sm);
  dw[wid][lane] = w0;
  if (lane + 64 < TOPK) dw[wid][lane + 64] = w1;
  __builtin_amdgcn_wave_barrier();

  // Phase C: PV, 8 keys per iteration, 3-step cross-group reduce
  const float* __restrict__ vbh = v + (size_t)b * Nn * DMm + h * DHh;
  float oa[8] = {};
#pragma unroll
  for (int it = 0; it < 13; ++it) {
    int s = it * 8 + g;
    if (s < TOPK) {
      float w = dw[wid][s];
      const float* __restrict__ vr = vbh + (size_t)sel[wid][s] * DMm + gl * 8;
      const float4 v0 = *(const float4*)vr;
      const float4 v1 = *(const float4*)(vr + 4);
      const float vv[8] = {v0.x, v0.y, v0.z, v0.w, v1.x, v1.y, v1.z, v1.w};
#pragma unroll
      for (int d = 0; d < 8; ++d) oa[d] = fmaf(w, vv[d], oa[d]);
    }
  }
#pragma unroll
  for (int s = 8; s < 64; s <<= 1) {
#pragma unroll
    for (int d = 0; d < 8; ++d) oa[d] += __shfl_xor(oa[d], s);
  }
  if (g == 0) {
    // fused epilogue: write bf16x2 planes (h,m) of ao
    const size_t off = (size_t)(b * Nn + n) * DMm + h * DHh + gl * 8;
    us4 h0, h1, m0v, m1v;
#pragma unroll
    for (int d = 0; d < 4; ++d) {
      unsigned short th, tm, tl;
      split3(oa[d] * inv, th, tm, tl);
      h0[d] = th; m0v[d] = tm;
      split3(oa[4 + d] * inv, th, tm, tl);
      h1[d] = th; m1v[d] = tm;
    }
    *(us4*)(aopl + off)               = h0;
    *(us4*)(aopl + off + 4)           = h1;
    *(us4*)(aopl + 1048576 + off)     = m0v;
    *(us4*)(aopl + 1048576 + off + 4) = m1v;
  }
}

// ---------------------------------------------------------------------------
extern "C" void kernel_launch(void* const* d_in, const int* in_sizes, int n_in,
                              void* d_out, int out_size, void* d_ws, size_t ws_size,
                              hipStream_t stream) {
  const float* x  = (const float*)d_in[0];
  const float* Wq = (const float*)d_in[1];
  const float* Wk = (const float*)d_in[2];
  const float* Wv = (const float*)d_in[3];
  const float* Wo = (const float*)d_in[4];
  const float* rv = (const float*)d_in[5];
  float* outp = (float*)d_out;

  const int RWS = Bb * Hh * Nn;  // 16384 (b,h,n) rows
  char* wsb = (char*)d_ws;
  float* q  = (float*)wsb;                 // 3 x 1M f32 (QKV)
  float* k  = q + 1048576;
  float* v  = k + 1048576;
  uint32_t* qh = (uint32_t*)(v + 1048576);
  uint32_t* kh = qh + RWS;
  float* qn = (float*)(kh + RWS);
  float* kn = qn + RWS;
  unsigned short* xpl = (unsigned short*)(wsb + (size_t)14 * 1024 * 1024);  // 3x1M halfs; reused as ao planes (h,m)
  unsigned short* wpl = xpl + (size_t)3 * 1048576;                          // 4x3x256K halfs

  cvt_split5<<<2048, 256, 0, stream>>>(x, Wq, Wk, Wv, Wo, xpl, wpl);
  dim3 gq(32, 24);               // QKV fused: z = blockIdx.y>>3 (z==2 -> 3 products)
  gemm_bf16x3<<<gq, 256, 0, stream>>>(xpl, wpl, q);
  hash_norm_kernel<<<RWS / 4, 256, 0, stream>>>(q, k, rv, qh, kh, qn, kn);
  attn_wave_kernel<<<RWS / 4, 256, 0, stream>>>(q, k, v, qh, kh, qn, kn, xpl);
  dim3 go(32, 8);
  gemm_ao_bf16x2<<<go, 256, 0, stream>>>(xpl, wpl + (size_t)3 * 786432, outp);
}